// Round 17
// baseline (582.014 us; speedup 1.0000x reference)
//
#include <hip/hip_runtime.h>
#include <hip/hip_bf16.h>
#include <stdint.h>

#define S_LEN 2048
#define D_MODEL 2048
#define NH 16
#define HD_DIM 128
#define BATCH 4

typedef unsigned short u16;
typedef unsigned int u32;
typedef short s16x8 __attribute__((ext_vector_type(8)));
typedef float f32x4 __attribute__((ext_vector_type(4)));
typedef float f32x16 __attribute__((ext_vector_type(16)));

__device__ __forceinline__ u16 f2b(float f) {
    union { float f; u32 u; } v; v.f = f;
    u32 r = v.u + 0x7FFFu + ((v.u >> 16) & 1u);
    return (u16)(r >> 16);
}

__device__ __forceinline__ u32 cvtpk(float lo, float hi) {
    u32 r;
    asm("v_cvt_pk_bf16_f32 %0, %1, %2" : "=v"(r) : "v"(lo), "v"(hi));
    return r;
}

__device__ __forceinline__ float exp2a(float x) {
    float r;
    asm("v_exp_f32 %0, %1" : "=v"(r) : "v"(x));
    return r;
}
__device__ __forceinline__ float max3a(float a, float b, float c) {
    float r;
    asm("v_max3_f32 %0, %1, %2, %3" : "=v"(r) : "v"(a), "v"(b), "v"(c));
    return r;
}

#define L2E 1.4426950408889634f

#define BAR()   asm volatile("s_barrier" ::: "memory")
#define LGKM0() asm volatile("s_waitcnt lgkmcnt(0)" ::: "memory")
#define VMW(n)  asm volatile("s_waitcnt vmcnt(" #n ")" ::: "memory")

// ---------------- single fused fp32->bf16 conversion launch ----------------
__global__ __launch_bounds__(256) void cvt_all(
    const float* __restrict__ wq, const float* __restrict__ wk,
    const float* __restrict__ wv, const float* __restrict__ wo,
    const float* __restrict__ q,  const float* __restrict__ k,
    const float* __restrict__ v,
    u16* __restrict__ wdst, u16* __restrict__ qdst,
    u16* __restrict__ kdst, u16* __restrict__ vdst) {
    int i = blockIdx.x * 256 + threadIdx.x;          // [0, 8388608)
    const float* src;
    u16* dst;
    if (i < 2097152) {                                // weights: 4 x 524288 n8-units
        const int seg = i >> 19, li = i & 524287;
        src = ((seg == 0) ? wq : (seg == 1) ? wk : (seg == 2) ? wv : wo) + (size_t)li * 8;
        dst = wdst + (size_t)i * 8;
    } else {                                          // activations: 3 x 2097152
        const int j = i - 2097152;
        const int seg = j >> 21, li = j & 2097151;
        src = ((seg == 0) ? q : (seg == 1) ? k : v) + (size_t)li * 8;
        dst = ((seg == 0) ? qdst : (seg == 1) ? kdst : vdst) + (size_t)li * 8;
    }
    const float4* p = reinterpret_cast<const float4*>(src);
    float4 a = p[0], b = p[1];
    s16x8 o;
    o[0] = (short)f2b(a.x); o[1] = (short)f2b(a.y);
    o[2] = (short)f2b(a.z); o[3] = (short)f2b(a.w);
    o[4] = (short)f2b(b.x); o[5] = (short)f2b(b.y);
    o[6] = (short)f2b(b.z); o[7] = (short)f2b(b.w);
    *reinterpret_cast<s16x8*>(dst) = o;
}

// ---------------- 256x256 8-phase NT GEMM (round-13/14 proven, unchanged) ----------------
template<int OUT_MODE>
__global__ __launch_bounds__(512, 1) void gemm256(const u16* __restrict__ Ab,
                                                  const u16* __restrict__ Bw,
                                                  void* __restrict__ Cv,
                                                  int M, int N, int K, float alpha) {
    __shared__ u16 lds[2][2][256 * 64];
    const int t = threadIdx.x, lane = t & 63, w = t >> 6;
    const int wm = w >> 2, wn = w & 3;
    const int lr = lane & 15, lk = lane >> 4;
    const int NT = K >> 6;

    const int ntile = N >> 8;
    int flat = blockIdx.x;
    int cpx = gridDim.x >> 3;
    int rmap = (flat & 7) * cpx + (flat >> 3);
    const int m0 = (rmap / ntile) * 256, n0 = (rmap % ntile) * 256;

    const int srow = t >> 3;
    const int spos = t & 7;
    const int scon = spos ^ (srow & 7);

    auto stage = [&](const u16* gbase, int grow0, int ldsT, int buf, int q, int kt) {
        const u16* src = gbase + (size_t)(grow0 + q * 64 + srow) * K + kt * 64 + scon * 8;
        u16* dst = &lds[buf][ldsT][(q * 64 + srow) * 64 + spos * 8];
        __builtin_amdgcn_global_load_lds(
            (const __attribute__((address_space(1))) void*)src,
            (__attribute__((address_space(3))) void*)dst, 16, 0, 0);
    };

    f32x4 acc[8][4];
#pragma unroll
    for (int i = 0; i < 8; ++i)
#pragma unroll
        for (int j = 0; j < 4; ++j) acc[i][j] = {0.f, 0.f, 0.f, 0.f};

    s16x8 a[4][2], b[4][2];

    stage(Bw, n0, 1, 0, 0, 0);
    stage(Bw, n0, 1, 0, 1, 0);
    stage(Bw, n0, 1, 0, 2, 0);
    stage(Bw, n0, 1, 0, 3, 0);
    stage(Ab, m0, 0, 0, 0, 0);
    stage(Ab, m0, 0, 0, 2, 0);
    stage(Ab, m0, 0, 0, 1, 0);
    stage(Ab, m0, 0, 0, 3, 0);
    VMW(2);
    BAR();

#define LDFRAG(base, row, kk) \
    (*(const s16x8*)((base) + (row) * 64 + ((((kk) * 4 + lk) ^ (lr & 7)) << 3)))

#define QUAD(mh, nh)                                                                   \
    __builtin_amdgcn_s_setprio(1);                                                     \
    _Pragma("unroll")                                                                  \
    for (int mf = 0; mf < 4; ++mf)                                                     \
        _Pragma("unroll")                                                              \
        for (int nf = 0; nf < 2; ++nf)                                                 \
            _Pragma("unroll")                                                          \
            for (int kk = 0; kk < 2; ++kk)                                             \
                acc[(mh) * 4 + mf][(nh) * 2 + nf] = __builtin_amdgcn_mfma_f32_16x16x32_bf16( \
                    a[mf][kk], b[(nh) * 2 + nf][kk], acc[(mh) * 4 + mf][(nh) * 2 + nf], 0, 0, 0); \
    __builtin_amdgcn_s_setprio(0);

    for (int kt = 0; kt < NT; ++kt) {
        const int buf = kt & 1;
        const u16* la = &lds[buf][0][0];
        const u16* lb = &lds[buf][1][0];
        const int nx = kt + 1;
        const bool st = nx < NT;

#pragma unroll
        for (int mf = 0; mf < 4; ++mf)
#pragma unroll
            for (int kk = 0; kk < 2; ++kk)
                a[mf][kk] = LDFRAG(la, wm * 128 + mf * 16 + lr, kk);
#pragma unroll
        for (int nf = 0; nf < 2; ++nf)
#pragma unroll
            for (int kk = 0; kk < 2; ++kk)
                b[nf][kk] = LDFRAG(lb, wn * 64 + nf * 16 + lr, kk);
        if (st) { stage(Bw, n0, 1, buf ^ 1, 0, nx); stage(Bw, n0, 1, buf ^ 1, 1, nx); }
        BAR();
        LGKM0();
        QUAD(0, 0);
        BAR();

#pragma unroll
        for (int nf = 2; nf < 4; ++nf)
#pragma unroll
            for (int kk = 0; kk < 2; ++kk)
                b[nf][kk] = LDFRAG(lb, wn * 64 + nf * 16 + lr, kk);
        if (st) { stage(Bw, n0, 1, buf ^ 1, 2, nx); stage(Bw, n0, 1, buf ^ 1, 3, nx); }
        BAR();
        LGKM0();
        QUAD(0, 1);
        if (kt == NT - 1) { VMW(0); } else { VMW(4); }
        BAR();

#pragma unroll
        for (int mf = 0; mf < 4; ++mf)
#pragma unroll
            for (int kk = 0; kk < 2; ++kk)
                a[mf][kk] = LDFRAG(la, wm * 128 + 64 + mf * 16 + lr, kk);
        if (st) { stage(Ab, m0, 0, buf ^ 1, 0, nx); stage(Ab, m0, 0, buf ^ 1, 2, nx); }
        BAR();
        LGKM0();
        QUAD(1, 0);
        BAR();

        if (st) { stage(Ab, m0, 0, buf ^ 1, 1, nx); stage(Ab, m0, 0, buf ^ 1, 3, nx); }
        BAR();
        QUAD(1, 1);
        VMW(2);
        BAR();
    }

#pragma unroll
    for (int i = 0; i < 8; ++i)
#pragma unroll
        for (int j = 0; j < 4; ++j) {
            int r0 = m0 + wm * 128 + (i >> 2) * 64 + (i & 3) * 16 + lk * 4;
            int c0 = n0 + wn * 64 + j * 16 + lr;
            if constexpr (OUT_MODE == 1) {
                float* C = (float*)Cv;
#pragma unroll
                for (int r = 0; r < 4; ++r) C[(size_t)(r0 + r) * N + c0] = acc[i][j][r] * alpha;
            } else {
                u16* C = (u16*)Cv;
#pragma unroll
                for (int r = 0; r < 4; ++r) C[(size_t)(r0 + r) * N + c0] = f2b(acc[i][j][r] * alpha);
            }
        }
}

// ---------------- flash attention: 32x32x16 MFMA core on the round-16 shell ----------------
// Staging (stageK/loadV/writeV), barriers, decode: byte-identical to round 16.
// Compute core rewritten on 32x32x16 (HW-verified C/D map: col=lane&31,
// row=(reg&3)+8*(reg>>2)+4*(lane>>5); A/B: elem k = 8*(lane>>5)+j):
//  - swapped QK (A=K,B=Q): lane owns one q-row (q=ln); kv halves across lane^32
//  - softmax: local max3 tree + ONE shfl_xor(32); log2 domain; defer-max
//  - P->A-frag: publish-select + 2 shfl_xor(32) per (kt,sel) = 8/tile
//    (replaces 32 ds_bpermutes of the 16x16 version)
//  - mask+kpad combined at prefetch (mc = mask+kpad) to hold VGPR budget flat
__global__ __launch_bounds__(512, 2) void attn_kernel(
    const u16* __restrict__ Qh, const u16* __restrict__ Kh, const u16* __restrict__ Vh,
    const float* __restrict__ mask, const float* __restrict__ kpad,
    u16* __restrict__ Comb) {
    __shared__ u16 Ks[2][64 * 128];
    __shared__ u16 Vt[2][128 * 64];

    const int t = threadIdx.x, lane = t & 63, w = t >> 6;   // w: 0..7
    const int ln = lane & 31, hi = lane >> 5;

    const int g = blockIdx.x;
    const int rm = (g & 7) * 64 + (g >> 3);      // 512 % 8 == 0: bijective
    const int qb = rm & 7, h = (rm >> 3) & 15, b = rm >> 7;  // qb fast (L3-friendly)
    const int q0w = qb * 256 + w * 32;
    const size_t rowBase = (size_t)b * S_LEN;
    const u16* Kb = Kh + rowBase * D_MODEL + h * HD_DIM;
    const u16* Vb = Vh + rowBase * D_MODEL + h * HD_DIM;

    // Q fragments (B operand): B[k=8hi+j][n=q=ln]; dsl covers d=128 in 16-k slices
    s16x8 qf[8];
    {
        const u16* qp = Qh + (rowBase + q0w + ln) * D_MODEL + h * HD_DIM + hi * 8;
#pragma unroll
        for (int dsl = 0; dsl < 8; ++dsl) qf[dsl] = *(const s16x8*)(qp + dsl * 16);
    }

    f32x16 o[4];
#pragma unroll
    for (int dt = 0; dt < 4; ++dt)
#pragma unroll
        for (int r = 0; r < 16; ++r) o[dt][r] = 0.f;
    float m_ = -3e38f, l_ = 0.f;

    // K staging (identical to round 16)
    const int ksub = t >> 4;
    const int kchunk = (t & 15) ^ (ksub & 7);
    // V staging (identical to round 16)
    const int vrow = t >> 3;
    const int vc0 = (t & 7) * 16;
    const int vodd = vrow & 1;
    const int vp = t >> 4;

    s16x8 va0, va1;

    auto stageK = [&](int kv0, int nb) {
#pragma unroll
        for (int p = 0; p < 2; ++p) {
            const u16* src = Kb + (size_t)(kv0 + p * 32 + ksub) * D_MODEL + kchunk * 8;
            __builtin_amdgcn_global_load_lds(
                (const __attribute__((address_space(1))) void*)src,
                (__attribute__((address_space(3))) void*)(&Ks[nb][p * 4096 + t * 8]), 16, 0, 0);
        }
    };
    auto loadV = [&](int kv0) {
        const u16* p0 = Vb + (size_t)(kv0 + vrow) * D_MODEL + vc0;
        va0 = *(const s16x8*)p0;
        va1 = *(const s16x8*)(p0 + 8);
    };
    auto writeV = [&](int nb) {
        union VU { s16x8 v[2]; u32 uw[8]; u16 us[16]; };
        VU A;
        A.v[0] = va0; A.v[1] = va1;
        u32 ra[4];
#pragma unroll
        for (int i = 0; i < 4; ++i)
            ra[i] = (u32)__shfl_xor((int)(vodd ? A.uw[i] : A.uw[i + 4]), 8, 64);
#pragma unroll
        for (int e = 0; e < 8; ++e) {
            int d = vc0 + vodd * 8 + e;
            int swz = ((d >> 4) ^ (d & 7)) & 7;
            u16 rau = (u16)((ra[e >> 1] >> ((e & 1) * 16)) & 0xffff);
            u16 lo1, hi1;
            if (vodd) { lo1 = rau; hi1 = A.us[8 + e]; }
            else      { lo1 = A.us[e]; hi1 = rau; }
            int c1 = (vp >> 2) ^ swz;
            *(u32*)(&Vt[nb][d * 64 + c1 * 8 + (vp & 3) * 2]) = (u32)lo1 | ((u32)hi1 << 16);
        }
    };

    // mask+kpad prefetch (one tile ahead), combined to keep VGPR flat:
    // mc[kt][g] covers cols kv0 + kt*32 + g*8 + hi*4 + {0..3} of row q0w+ln
    f32x4 mc[2][4];
    f32x4 mt[2][4], kt_[2][4];
    auto loadMask = [&](int kv0) {
        const float* mrow = mask + (size_t)(q0w + ln) * S_LEN + kv0;
        const float* krow = kpad + (size_t)b * S_LEN + kv0;
#pragma unroll
        for (int kk = 0; kk < 2; ++kk)
#pragma unroll
            for (int gg = 0; gg < 4; ++gg) {
                mt[kk][gg] = *(const f32x4*)(mrow + kk * 32 + gg * 8 + hi * 4);
                kt_[kk][gg] = *(const f32x4*)(krow + kk * 32 + gg * 8 + hi * 4);
            }
    };
    auto combMask = [&]() {
#pragma unroll
        for (int kk = 0; kk < 2; ++kk)
#pragma unroll
            for (int gg = 0; gg < 4; ++gg) mc[kk][gg] = mt[kk][gg] + kt_[kk][gg];
    };

    // prologue
    stageK(0, 0);
    loadV(0);
    writeV(0);
    loadMask(0);
    __syncthreads();
    combMask();

    for (int i = 0; i < 32; ++i) {
        const int cur = i & 1;
        const u16* ks = &Ks[cur][0];
        const u16* vt = &Vt[cur][0];
        const int kv0 = i * 64;

        if (i < 31) { stageK(kv0 + 64, cur ^ 1); loadV(kv0 + 64); }

        // QK^T (swapped): sc[kt][r] = S[kv = kt*32 + (r&3)+8*(r>>2)+4*hi][q = ln]
        f32x16 sc[2];
#pragma unroll
        for (int kk = 0; kk < 2; ++kk)
#pragma unroll
            for (int r = 0; r < 16; ++r) sc[kk][r] = 0.f;
        __builtin_amdgcn_s_setprio(1);
#pragma unroll
        for (int kk = 0; kk < 2; ++kk)
#pragma unroll
            for (int dsl = 0; dsl < 8; ++dsl) {
                s16x8 kf = *(const s16x8*)(&ks[(kk * 32 + ln) * 128 +
                                               (((dsl * 2 + hi) ^ (ln & 7)) << 3)]);
                sc[kk] = __builtin_amdgcn_mfma_f32_32x32x16_bf16(kf, qf[dsl], sc[kk], 0, 0, 0);
            }
        __builtin_amdgcn_s_setprio(0);

        // scores (log2 domain: mc folded via one fma) + row max
        float s[32];
#pragma unroll
        for (int kk = 0; kk < 2; ++kk)
#pragma unroll
            for (int r = 0; r < 16; ++r)
                s[kk * 16 + r] = fmaf(mc[kk][r >> 2][r & 3], L2E, sc[kk][r]);

        float t0 = max3a(s[0], s[1], s[2]);
        float t1 = max3a(s[3], s[4], s[5]);
        float t2 = max3a(s[6], s[7], s[8]);
        float t3 = max3a(s[9], s[10], s[11]);
        float t4 = max3a(s[12], s[13], s[14]);
        float t5 = max3a(s[15], s[16], s[17]);
        float t6 = max3a(s[18], s[19], s[20]);
        float t7 = max3a(s[21], s[22], s[23]);
        float t8 = max3a(s[24], s[25], s[26]);
        float t9 = max3a(s[27], s[28], s[29]);
        float ua = max3a(t0, t1, t2);
        float ub = max3a(t3, t4, t5);
        float uc = max3a(t6, t7, t8);
        float ud = max3a(t9, s[30], s[31]);
        float rmax = fmaxf(max3a(ua, ub, uc), ud);
        rmax = fmaxf(rmax, __shfl_xor(rmax, 32, 64));

        // defer-max (T13): 11.5 log2-units ~= 8 e-units
        if (__any(rmax > m_ + 11.5f)) {
            float mn = fmaxf(m_, rmax);
            float fs = exp2a(m_ - mn);
            m_ = mn;
            l_ *= fs;
#pragma unroll
            for (int r = 0; r < 16; ++r) {
                float fsb = __shfl(fs, (r & 3) + 8 * (r >> 2) + 4 * hi, 64);
#pragma unroll
                for (int dt = 0; dt < 4; ++dt) o[dt][r] *= fsb;
            }
        }

        float ls = 0.f;
#pragma unroll
        for (int e = 0; e < 32; ++e) { s[e] = exp2a(s[e] - m_); ls += s[e]; }
        ls += __shfl_xor(ls, 32, 64);
        l_ += ls;

        // pack P to bf16 pairs: wd[kt][p] covers kv = 32kt + 8*(p>>1) + 4hi + 2*(p&1) + {0,1}
        u32 wd[2][8];
#pragma unroll
        for (int kk = 0; kk < 2; ++kk)
#pragma unroll
            for (int p = 0; p < 8; ++p)
                wd[kk][p] = cvtpk(s[kk * 16 + 2 * p], s[kk * 16 + 2 * p + 1]);

        // prefetch next tile's mask/kpad (mc consumed; mt/kt_ regs free)
        if (i < 31) loadMask(kv0 + 64);

        // exchange + PV: A-frag[ks4].u[m] needs kv = 16*ks4 + 8*hi + 2m + {0,1}
        __builtin_amdgcn_s_setprio(1);
#pragma unroll
        for (int kk = 0; kk < 2; ++kk)
#pragma unroll
            for (int sel = 0; sel < 2; ++sel) {
                u32 pub0 = hi ? wd[kk][4 * sel + 0] : wd[kk][4 * sel + 2];
                u32 pub1 = hi ? wd[kk][4 * sel + 1] : wd[kk][4 * sel + 3];
                u32 r0 = (u32)__shfl_xor((int)pub0, 32, 64);
                u32 r1 = (u32)__shfl_xor((int)pub1, 32, 64);
                union { s16x8 v; u32 u[4]; } P;
                P.u[0] = hi ? r0 : wd[kk][4 * sel + 0];
                P.u[1] = hi ? r1 : wd[kk][4 * sel + 1];
                P.u[2] = hi ? wd[kk][4 * sel + 2] : r0;
                P.u[3] = hi ? wd[kk][4 * sel + 3] : r1;
                const int ks4 = kk * 2 + sel;
#pragma unroll
                for (int dt = 0; dt < 4; ++dt) {
                    int d = dt * 32 + ln;
                    s16x8 vf = *(const s16x8*)(&vt[d * 64 +
                                (((2 * ks4 + hi) ^ (((d >> 4) ^ d) & 7)) << 3)]);
                    o[dt] = __builtin_amdgcn_mfma_f32_32x32x16_bf16(P.v, vf, o[dt], 0, 0, 0);
                }
            }
        __builtin_amdgcn_s_setprio(0);

        if (i < 31) writeV(cur ^ 1);
        LGKM0();
        BAR();
        if (i < 31) combMask();
    }

    // epilogue: o[dt][r]: q = q0w + (r&3)+8*(r>>2)+4*hi, d = dt*32 + ln
    float inv = 1.0f / l_;
#pragma unroll
    for (int r = 0; r < 16; ++r) {
        int qrow = (r & 3) + 8 * (r >> 2) + 4 * hi;
        float invq = __shfl(inv, qrow, 64);
        size_t row = rowBase + q0w + qrow;
        u16* dst = Comb + row * D_MODEL + h * HD_DIM + ln;
#pragma unroll
        for (int dt = 0; dt < 4; ++dt) dst[dt * 32] = f2b(o[dt][r] * invq);
    }
}

extern "C" void kernel_launch(void* const* d_in, const int* in_sizes, int n_in,
                              void* d_out, int out_size, void* d_ws, size_t ws_size,
                              hipStream_t stream) {
    const float* q    = (const float*)d_in[0];
    const float* k    = (const float*)d_in[1];
    const float* v    = (const float*)d_in[2];
    const float* mask = (const float*)d_in[3];
    const float* kpad = (const float*)d_in[4];
    const float* wq   = (const float*)d_in[5];
    const float* wk   = (const float*)d_in[6];
    const float* wv   = (const float*)d_in[7];
    const float* wo   = (const float*)d_in[8];
    float* out = (float*)d_out;

    u16* wqb  = (u16*)d_ws;                 // 2048*2048 bf16 each, contiguous x4
    u16* wkb  = wqb + 4194304;
    u16* wvb  = wkb + 4194304;
    u16* wob  = wvb + 4194304;
    u16* qh   = wob + 4194304;              // 8192*2048 bf16 each
    u16* kh   = qh + 16777216;
    u16* vh   = kh + 16777216;
    u16* comb = vh + 16777216;
    // total: 160 MB

    // 1/sqrt(128) * log2(e): Q-projection alpha puts QK^T scores in log2 domain
    const float scale = 0.08838834764831845f * 1.4426950408889634f;

    {
        dim3 gc(8388608 / 256);
        cvt_all<<<gc, 256, 0, stream>>>(wq, wk, wv, wo, q, k, v, wqb, kh, vh, comb);
    }
    dim3 gg((8192 / 256) * (2048 / 256));   // 256 blocks

    gemm256<0><<<gg, 512, 0, stream>>>(kh,   wqb, qh, 8192, 2048, 2048, scale);  // Q proj
    gemm256<0><<<gg, 512, 0, stream>>>(vh,   wkb, kh, 8192, 2048, 2048, 1.0f);   // K proj
    gemm256<0><<<gg, 512, 0, stream>>>(comb, wvb, vh, 8192, 2048, 2048, 1.0f);   // V proj

    attn_kernel<<<dim3(512), 512, 0, stream>>>(qh, kh, vh, mask, kpad, comb);

    gemm256<1><<<gg, 512, 0, stream>>>(comb, wob, out, 8192, 2048, 2048, 1.0f);  // O proj
}

// Round 18
// 565.616 us; speedup vs baseline: 1.0290x; 1.0290x over previous
//
#include <hip/hip_runtime.h>
#include <hip/hip_bf16.h>
#include <stdint.h>

#define S_LEN 2048
#define D_MODEL 2048
#define NH 16
#define HD_DIM 128
#define BATCH 4

typedef unsigned short u16;
typedef unsigned int u32;
typedef short s16x8 __attribute__((ext_vector_type(8)));
typedef float f32x4 __attribute__((ext_vector_type(4)));

__device__ __forceinline__ u16 f2b(float f) {
    union { float f; u32 u; } v; v.f = f;
    u32 r = v.u + 0x7FFFu + ((v.u >> 16) & 1u);
    return (u16)(r >> 16);
}

__device__ __forceinline__ u32 cvtpk(float lo, float hi) {
    u32 r;
    asm("v_cvt_pk_bf16_f32 %0, %1, %2" : "=v"(r) : "v"(lo), "v"(hi));
    return r;
}

// pure (non-volatile) single-instruction helpers — schedulable/CSE-able
__device__ __forceinline__ float exp2a(float x) {
    float r;
    asm("v_exp_f32 %0, %1" : "=v"(r) : "v"(x));
    return r;
}
__device__ __forceinline__ float max3a(float a, float b, float c) {
    float r;
    asm("v_max3_f32 %0, %1, %2, %3" : "=v"(r) : "v"(a), "v"(b), "v"(c));
    return r;
}

#define L2E 1.4426950408889634f

#define BAR()   asm volatile("s_barrier" ::: "memory")
#define LGKM0() asm volatile("s_waitcnt lgkmcnt(0)" ::: "memory")
#define VMW(n)  asm volatile("s_waitcnt vmcnt(" #n ")" ::: "memory")

// ---------------- single fused fp32->bf16 conversion launch ----------------
// Converts all 4 weight matrices (-> wqb, contiguous) AND q,k,v activations.
// Activation dsts chained into soon-to-be-overwritten GEMM buffers
// (q->kh, k->vh, v->comb): at every later step read-buf != write-buf.
__global__ __launch_bounds__(256) void cvt_all(
    const float* __restrict__ wq, const float* __restrict__ wk,
    const float* __restrict__ wv, const float* __restrict__ wo,
    const float* __restrict__ q,  const float* __restrict__ k,
    const float* __restrict__ v,
    u16* __restrict__ wdst, u16* __restrict__ qdst,
    u16* __restrict__ kdst, u16* __restrict__ vdst) {
    int i = blockIdx.x * 256 + threadIdx.x;          // [0, 8388608)
    const float* src;
    u16* dst;
    if (i < 2097152) {                                // weights: 4 x 524288 n8-units
        const int seg = i >> 19, li = i & 524287;
        src = ((seg == 0) ? wq : (seg == 1) ? wk : (seg == 2) ? wv : wo) + (size_t)li * 8;
        dst = wdst + (size_t)i * 8;
    } else {                                          // activations: 3 x 2097152
        const int j = i - 2097152;
        const int seg = j >> 21, li = j & 2097151;
        src = ((seg == 0) ? q : (seg == 1) ? k : v) + (size_t)li * 8;
        dst = ((seg == 0) ? qdst : (seg == 1) ? kdst : vdst) + (size_t)li * 8;
    }
    const float4* p = reinterpret_cast<const float4*>(src);
    float4 a = p[0], b = p[1];
    s16x8 o;
    o[0] = (short)f2b(a.x); o[1] = (short)f2b(a.y);
    o[2] = (short)f2b(a.z); o[3] = (short)f2b(a.w);
    o[4] = (short)f2b(b.x); o[5] = (short)f2b(b.y);
    o[6] = (short)f2b(b.z); o[7] = (short)f2b(b.w);
    *reinterpret_cast<s16x8*>(dst) = o;
}

// ---------------- 256x256 8-phase NT GEMM (round-13/14 proven, unchanged) ----------------
template<int OUT_MODE>
__global__ __launch_bounds__(512, 1) void gemm256(const u16* __restrict__ Ab,
                                                  const u16* __restrict__ Bw,
                                                  void* __restrict__ Cv,
                                                  int M, int N, int K, float alpha) {
    __shared__ u16 lds[2][2][256 * 64];
    const int t = threadIdx.x, lane = t & 63, w = t >> 6;
    const int wm = w >> 2, wn = w & 3;
    const int lr = lane & 15, lk = lane >> 4;
    const int NT = K >> 6;

    const int ntile = N >> 8;
    int flat = blockIdx.x;
    int cpx = gridDim.x >> 3;
    int rmap = (flat & 7) * cpx + (flat >> 3);
    const int m0 = (rmap / ntile) * 256, n0 = (rmap % ntile) * 256;

    const int srow = t >> 3;
    const int spos = t & 7;
    const int scon = spos ^ (srow & 7);

    auto stage = [&](const u16* gbase, int grow0, int ldsT, int buf, int q, int kt) {
        const u16* src = gbase + (size_t)(grow0 + q * 64 + srow) * K + kt * 64 + scon * 8;
        u16* dst = &lds[buf][ldsT][(q * 64 + srow) * 64 + spos * 8];
        __builtin_amdgcn_global_load_lds(
            (const __attribute__((address_space(1))) void*)src,
            (__attribute__((address_space(3))) void*)dst, 16, 0, 0);
    };

    f32x4 acc[8][4];
#pragma unroll
    for (int i = 0; i < 8; ++i)
#pragma unroll
        for (int j = 0; j < 4; ++j) acc[i][j] = {0.f, 0.f, 0.f, 0.f};

    s16x8 a[4][2], b[4][2];

    stage(Bw, n0, 1, 0, 0, 0);
    stage(Bw, n0, 1, 0, 1, 0);
    stage(Bw, n0, 1, 0, 2, 0);
    stage(Bw, n0, 1, 0, 3, 0);
    stage(Ab, m0, 0, 0, 0, 0);
    stage(Ab, m0, 0, 0, 2, 0);
    stage(Ab, m0, 0, 0, 1, 0);
    stage(Ab, m0, 0, 0, 3, 0);
    VMW(2);
    BAR();

#define LDFRAG(base, row, kk) \
    (*(const s16x8*)((base) + (row) * 64 + ((((kk) * 4 + lk) ^ (lr & 7)) << 3)))

#define QUAD(mh, nh)                                                                   \
    __builtin_amdgcn_s_setprio(1);                                                     \
    _Pragma("unroll")                                                                  \
    for (int mf = 0; mf < 4; ++mf)                                                     \
        _Pragma("unroll")                                                              \
        for (int nf = 0; nf < 2; ++nf)                                                 \
            _Pragma("unroll")                                                          \
            for (int kk = 0; kk < 2; ++kk)                                             \
                acc[(mh) * 4 + mf][(nh) * 2 + nf] = __builtin_amdgcn_mfma_f32_16x16x32_bf16( \
                    a[mf][kk], b[(nh) * 2 + nf][kk], acc[(mh) * 4 + mf][(nh) * 2 + nf], 0, 0, 0); \
    __builtin_amdgcn_s_setprio(0);

    for (int kt = 0; kt < NT; ++kt) {
        const int buf = kt & 1;
        const u16* la = &lds[buf][0][0];
        const u16* lb = &lds[buf][1][0];
        const int nx = kt + 1;
        const bool st = nx < NT;

#pragma unroll
        for (int mf = 0; mf < 4; ++mf)
#pragma unroll
            for (int kk = 0; kk < 2; ++kk)
                a[mf][kk] = LDFRAG(la, wm * 128 + mf * 16 + lr, kk);
#pragma unroll
        for (int nf = 0; nf < 2; ++nf)
#pragma unroll
            for (int kk = 0; kk < 2; ++kk)
                b[nf][kk] = LDFRAG(lb, wn * 64 + nf * 16 + lr, kk);
        if (st) { stage(Bw, n0, 1, buf ^ 1, 0, nx); stage(Bw, n0, 1, buf ^ 1, 1, nx); }
        BAR();
        LGKM0();
        QUAD(0, 0);
        BAR();

#pragma unroll
        for (int nf = 2; nf < 4; ++nf)
#pragma unroll
            for (int kk = 0; kk < 2; ++kk)
                b[nf][kk] = LDFRAG(lb, wn * 64 + nf * 16 + lr, kk);
        if (st) { stage(Bw, n0, 1, buf ^ 1, 2, nx); stage(Bw, n0, 1, buf ^ 1, 3, nx); }
        BAR();
        LGKM0();
        QUAD(0, 1);
        if (kt == NT - 1) { VMW(0); } else { VMW(4); }
        BAR();

#pragma unroll
        for (int mf = 0; mf < 4; ++mf)
#pragma unroll
            for (int kk = 0; kk < 2; ++kk)
                a[mf][kk] = LDFRAG(la, wm * 128 + 64 + mf * 16 + lr, kk);
        if (st) { stage(Ab, m0, 0, buf ^ 1, 0, nx); stage(Ab, m0, 0, buf ^ 1, 2, nx); }
        BAR();
        LGKM0();
        QUAD(1, 0);
        BAR();

        if (st) { stage(Ab, m0, 0, buf ^ 1, 1, nx); stage(Ab, m0, 0, buf ^ 1, 3, nx); }
        BAR();
        QUAD(1, 1);
        VMW(2);
        BAR();
    }

#pragma unroll
    for (int i = 0; i < 8; ++i)
#pragma unroll
        for (int j = 0; j < 4; ++j) {
            int r0 = m0 + wm * 128 + (i >> 2) * 64 + (i & 3) * 16 + lk * 4;
            int c0 = n0 + wn * 64 + j * 16 + lr;
            if constexpr (OUT_MODE == 1) {
                float* C = (float*)Cv;
#pragma unroll
                for (int r = 0; r < 4; ++r) C[(size_t)(r0 + r) * N + c0] = acc[i][j][r] * alpha;
            } else {
                u16* C = (u16*)Cv;
#pragma unroll
                for (int r = 0; r < 4; ++r) C[(size_t)(r0 + r) * N + c0] = f2b(acc[i][j][r] * alpha);
            }
        }
}

// ---------------- flash attention (round-16 winner + tree-sum softmax) ----------------
// Structure byte-identical to round 16 (16x16x32 core, V dbuf LDS shfl-transpose,
// K dbuf gload_lds, counted-wait tile barrier, defer-max, mask/kpad reg-prefetch,
// log2-domain softmax, max3 trees). ONE change from round-17's lesson (dependency
// depth, not op count, limits this kernel): the 16-deep serial ls accumulation
// becomes a 4-level pairwise tree per qi.
__global__ __launch_bounds__(512, 2) void attn_kernel(
    const u16* __restrict__ Qh, const u16* __restrict__ Kh, const u16* __restrict__ Vh,
    const float* __restrict__ mask, const float* __restrict__ kpad,
    u16* __restrict__ Comb) {
    __shared__ u16 Ks[2][64 * 128];
    __shared__ u16 Vt[2][128 * 64];

    const int t = threadIdx.x, lane = t & 63, w = t >> 6;   // w: 0..7
    const int lr = lane & 15, lk = lane >> 4;

    const int g = blockIdx.x;
    const int rm = (g & 7) * 64 + (g >> 3);      // 512 % 8 == 0: bijective
    const int qb = rm & 7, h = (rm >> 3) & 15, b = rm >> 7;  // qb fast (L3-friendly)
    const int q0w = qb * 256 + w * 32;
    const size_t rowBase = (size_t)b * S_LEN;
    const u16* Kb = Kh + rowBase * D_MODEL + h * HD_DIM;
    const u16* Vb = Vh + rowBase * D_MODEL + h * HD_DIM;

    // Q fragments (B operand): q = q0w + qi*16 + lr, d = dc*32 + lk*8 + j.
    // (scale*log2e pre-folded into the Q projection)
    s16x8 qf[2][4];
#pragma unroll
    for (int qi = 0; qi < 2; ++qi)
#pragma unroll
        for (int dc = 0; dc < 4; ++dc)
            qf[qi][dc] = *(const s16x8*)(Qh + (rowBase + q0w + qi * 16 + lr) * D_MODEL +
                                         h * HD_DIM + dc * 32 + lk * 8);

    f32x4 o[2][8];
#pragma unroll
    for (int qi = 0; qi < 2; ++qi)
#pragma unroll
        for (int dt = 0; dt < 8; ++dt) o[qi][dt] = {0.f, 0.f, 0.f, 0.f};
    float m_[2] = {-3e38f, -3e38f}, l_[2] = {0.f, 0.f};

    // K staging (512 threads, 2 passes of 32 rows)
    const int ksub = t >> 4;                          // 0..31
    const int kchunk = (t & 15) ^ (ksub & 7);         // pre-swizzled global chunk
    // V staging (512 threads, one pass covers all 64 kv rows)
    const int vrow = t >> 3;                          // 0..63
    const int vc0 = (t & 7) * 16;
    const int vodd = vrow & 1;
    const int vp = t >> 4;                            // kv-pair 0..31

    s16x8 va0, va1;

    auto stageK = [&](int kv0, int nb) {
#pragma unroll
        for (int p = 0; p < 2; ++p) {
            const u16* src = Kb + (size_t)(kv0 + p * 32 + ksub) * D_MODEL + kchunk * 8;
            __builtin_amdgcn_global_load_lds(
                (const __attribute__((address_space(1))) void*)src,
                (__attribute__((address_space(3))) void*)(&Ks[nb][p * 4096 + t * 8]), 16, 0, 0);
        }
    };
    auto loadV = [&](int kv0) {
        const u16* p0 = Vb + (size_t)(kv0 + vrow) * D_MODEL + vc0;
        va0 = *(const s16x8*)p0;
        va1 = *(const s16x8*)(p0 + 8);
    };
    auto writeV = [&](int nb) {
        union VU { s16x8 v[2]; u32 uw[8]; u16 us[16]; };
        VU A;
        A.v[0] = va0; A.v[1] = va1;
        u32 ra[4];
#pragma unroll
        for (int i = 0; i < 4; ++i)
            ra[i] = (u32)__shfl_xor((int)(vodd ? A.uw[i] : A.uw[i + 4]), 8, 64);
#pragma unroll
        for (int e = 0; e < 8; ++e) {
            int d = vc0 + vodd * 8 + e;
            int swz = ((d >> 4) ^ (d & 7)) & 7;
            u16 rau = (u16)((ra[e >> 1] >> ((e & 1) * 16)) & 0xffff);
            u16 lo1, hi1;
            if (vodd) { lo1 = rau; hi1 = A.us[8 + e]; }
            else      { lo1 = A.us[e]; hi1 = rau; }
            int c1 = (vp >> 2) ^ swz;
            *(u32*)(&Vt[nb][d * 64 + c1 * 8 + (vp & 3) * 2]) = (u32)lo1 | ((u32)hi1 << 16);
        }
    };

    // mask/kpad register prefetch (one tile ahead)
    f32x4 mreg[2][4], kreg[4];
    auto loadMask = [&](int kv0) {
#pragma unroll
        for (int qi = 0; qi < 2; ++qi) {
            const float* mrow = mask + (size_t)(q0w + qi * 16 + lr) * S_LEN + kv0;
#pragma unroll
            for (int kt = 0; kt < 4; ++kt)
                mreg[qi][kt] = *(const f32x4*)(mrow + kt * 16 + lk * 4);
        }
#pragma unroll
        for (int kt = 0; kt < 4; ++kt)
            kreg[kt] = *(const f32x4*)(kpad + b * S_LEN + kv0 + kt * 16 + lk * 4);
    };

    // prologue: stage tile 0 (full drain once)
    stageK(0, 0);
    loadV(0);
    writeV(0);
    loadMask(0);
    __syncthreads();

    const int srcA = ((lk & 1) * 32) + lr;   // lane holding lk' = (lk&1)*2
    const int srcB = srcA + 16;

    for (int i = 0; i < 32; ++i) {
        const int cur = i & 1;
        const u16* ks = &Ks[cur][0];
        const u16* vt = &Vt[cur][0];
        const int kv0 = i * 64;

        if (i < 31) { stageK(kv0 + 64, cur ^ 1); loadV(kv0 + 64); }

        // QK^T (swapped): sc[qi][kt]: lane holds S[kv=kt*16+lk*4+r][q=qi*16+lr]
        f32x4 sc[2][4];
#pragma unroll
        for (int qi = 0; qi < 2; ++qi)
#pragma unroll
            for (int kt = 0; kt < 4; ++kt) sc[qi][kt] = {0.f, 0.f, 0.f, 0.f};
        __builtin_amdgcn_s_setprio(1);
#pragma unroll
        for (int kt = 0; kt < 4; ++kt) {
            s16x8 kf[4];
#pragma unroll
            for (int dc = 0; dc < 4; ++dc)
                kf[dc] = *(const s16x8*)(&ks[(kt * 16 + lr) * 128 +
                                             (((dc * 4 + lk) ^ (lr & 7)) << 3)]);
#pragma unroll
            for (int dc = 0; dc < 4; ++dc) {
                sc[0][kt] = __builtin_amdgcn_mfma_f32_16x16x32_bf16(kf[dc], qf[0][dc], sc[0][kt], 0, 0, 0);
                sc[1][kt] = __builtin_amdgcn_mfma_f32_16x16x32_bf16(kf[dc], qf[1][dc], sc[1][kt], 0, 0, 0);
            }
        }
        __builtin_amdgcn_s_setprio(0);

        // masks (prefetched regs, folded *log2e via fma) + online softmax (log2 domain)
        u32 lo[2][4], hi[2][4];
#pragma unroll
        for (int qi = 0; qi < 2; ++qi) {
            float s[16];
#pragma unroll
            for (int kt = 0; kt < 4; ++kt)
#pragma unroll
                for (int r = 0; r < 4; ++r)
                    s[kt * 4 + r] = fmaf(mreg[qi][kt][r], L2E,
                                         fmaf(kreg[kt][r], L2E, sc[qi][kt][r]));
            float t0 = max3a(s[0], s[1], s[2]);
            float t1 = max3a(s[3], s[4], s[5]);
            float t2 = max3a(s[6], s[7], s[8]);
            float t3 = max3a(s[9], s[10], s[11]);
            float t4 = max3a(s[12], s[13], s[14]);
            float mx = fmaxf(max3a(t0, t1, t2), max3a(t3, t4, s[15]));
            mx = fmaxf(mx, __shfl_xor(mx, 16, 64));
            mx = fmaxf(mx, __shfl_xor(mx, 32, 64));
            // defer-max (T13): 11.5 log2-units ~= 8 e-units
            if (__any(mx > m_[qi] + 11.5f)) {
                float mn = fmaxf(m_[qi], mx);
                float fs = exp2a(m_[qi] - mn);
                m_[qi] = mn;
                l_[qi] *= fs;
#pragma unroll
                for (int r = 0; r < 4; ++r) {
                    float fsb = __shfl(fs, (lane & 48) | (lk * 4 + r), 64);
#pragma unroll
                    for (int dt = 0; dt < 8; ++dt) o[qi][dt][r] *= fsb;
                }
            }
#pragma unroll
            for (int e = 0; e < 16; ++e) s[e] = exp2a(s[e] - m_[qi]);
            // pairwise tree-sum: dependency depth 4 instead of 16
            float p0 = (s[0] + s[1]) + (s[2] + s[3]);
            float p1 = (s[4] + s[5]) + (s[6] + s[7]);
            float p2 = (s[8] + s[9]) + (s[10] + s[11]);
            float p3 = (s[12] + s[13]) + (s[14] + s[15]);
            float ls = (p0 + p1) + (p2 + p3);
            ls += __shfl_xor(ls, 16, 64);
            ls += __shfl_xor(ls, 32, 64);
            l_[qi] += ls;
#pragma unroll
            for (int kt = 0; kt < 4; ++kt) {
                lo[qi][kt] = cvtpk(s[kt * 4 + 0], s[kt * 4 + 1]);
                hi[qi][kt] = cvtpk(s[kt * 4 + 2], s[kt * 4 + 3]);
            }
        }

        // prefetch next tile's mask/kpad (regs free after s[] computed above)
        if (i < 31) loadMask(kv0 + 64);

        // redistribute P (C-layout) -> A-frag in-register
        s16x8 pf[2][2];
        const bool sel = (lk >> 1) & 1;
#pragma unroll
        for (int qi = 0; qi < 2; ++qi)
#pragma unroll
            for (int hh = 0; hh < 2; ++hh) {
                u32 w0a = (u32)__shfl((int)lo[qi][2 * hh], srcA, 64);
                u32 w0b = (u32)__shfl((int)lo[qi][2 * hh + 1], srcA, 64);
                u32 w1a = (u32)__shfl((int)hi[qi][2 * hh], srcA, 64);
                u32 w1b = (u32)__shfl((int)hi[qi][2 * hh + 1], srcA, 64);
                u32 w2a = (u32)__shfl((int)lo[qi][2 * hh], srcB, 64);
                u32 w2b = (u32)__shfl((int)lo[qi][2 * hh + 1], srcB, 64);
                u32 w3a = (u32)__shfl((int)hi[qi][2 * hh], srcB, 64);
                u32 w3b = (u32)__shfl((int)hi[qi][2 * hh + 1], srcB, 64);
                union { s16x8 v; u32 u[4]; } P;
                P.u[0] = sel ? w0b : w0a;
                P.u[1] = sel ? w1b : w1a;
                P.u[2] = sel ? w2b : w2a;
                P.u[3] = sel ? w3b : w3a;
                pf[qi][hh] = P.v;
            }

        // PV: o[qi][dt] += P[16x64] @ V[64x16]
        __builtin_amdgcn_s_setprio(1);
#pragma unroll
        for (int dt = 0; dt < 8; ++dt) {
            int swz = dt ^ (lr & 7);
            s16x8 vf0 = *(const s16x8*)(&vt[(dt * 16 + lr) * 64 + ((lk ^ swz) << 3)]);
            s16x8 vf1 = *(const s16x8*)(&vt[(dt * 16 + lr) * 64 + (((4 + lk) ^ swz) << 3)]);
            o[0][dt] = __builtin_amdgcn_mfma_f32_16x16x32_bf16(pf[0][0], vf0, o[0][dt], 0, 0, 0);
            o[1][dt] = __builtin_amdgcn_mfma_f32_16x16x32_bf16(pf[1][0], vf0, o[1][dt], 0, 0, 0);
            o[0][dt] = __builtin_amdgcn_mfma_f32_16x16x32_bf16(pf[0][1], vf1, o[0][dt], 0, 0, 0);
            o[1][dt] = __builtin_amdgcn_mfma_f32_16x16x32_bf16(pf[1][1], vf1, o[1][dt], 0, 0, 0);
        }
        __builtin_amdgcn_s_setprio(0);

        if (i < 31) writeV(cur ^ 1);
        LGKM0();
        BAR();
    }

    // epilogue: O = o / l; o C-layout: q = qi*16 + lk*4 + r, d = dt*16 + lr
#pragma unroll
    for (int qi = 0; qi < 2; ++qi)
#pragma unroll
        for (int r = 0; r < 4; ++r) {
            float lb = __shfl(l_[qi], (lane & 48) | (lk * 4 + r), 64);
            float inv = 1.0f / lb;
            size_t row = rowBase + q0w + qi * 16 + lk * 4 + r;
            u16* dst = Comb + row * D_MODEL + h * HD_DIM + lr;
#pragma unroll
            for (int dt = 0; dt < 8; ++dt) dst[dt * 16] = f2b(o[qi][dt][r] * inv);
        }
}

extern "C" void kernel_launch(void* const* d_in, const int* in_sizes, int n_in,
                              void* d_out, int out_size, void* d_ws, size_t ws_size,
                              hipStream_t stream) {
    const float* q    = (const float*)d_in[0];
    const float* k    = (const float*)d_in[1];
    const float* v    = (const float*)d_in[2];
    const float* mask = (const float*)d_in[3];
    const float* kpad = (const float*)d_in[4];
    const float* wq   = (const float*)d_in[5];
    const float* wk   = (const float*)d_in[6];
    const float* wv   = (const float*)d_in[7];
    const float* wo   = (const float*)d_in[8];
    float* out = (float*)d_out;

    u16* wqb  = (u16*)d_ws;                 // 2048*2048 bf16 each, contiguous x4
    u16* wkb  = wqb + 4194304;
    u16* wvb  = wkb + 4194304;
    u16* wob  = wvb + 4194304;
    u16* qh   = wob + 4194304;              // 8192*2048 bf16 each
    u16* kh   = qh + 16777216;
    u16* vh   = kh + 16777216;
    u16* comb = vh + 16777216;
    // total: 160 MB

    // 1/sqrt(128) * log2(e): Q-projection alpha puts QK^T scores in log2 domain
    const float scale = 0.08838834764831845f * 1.4426950408889634f;

    {
        dim3 gc(8388608 / 256);
        cvt_all<<<gc, 256, 0, stream>>>(wq, wk, wv, wo, q, k, v, wqb, kh, vh, comb);
    }
    dim3 gg((8192 / 256) * (2048 / 256));   // 256 blocks

    gemm256<0><<<gg, 512, 0, stream>>>(kh,   wqb, qh, 8192, 2048, 2048, scale);  // Q proj
    gemm256<0><<<gg, 512, 0, stream>>>(vh,   wkb, kh, 8192, 2048, 2048, 1.0f);   // K proj
    gemm256<0><<<gg, 512, 0, stream>>>(comb, wvb, vh, 8192, 2048, 2048, 1.0f);   // V proj

    attn_kernel<<<dim3(512), 512, 0, stream>>>(qh, kh, vh, mask, kpad, comb);

    gemm256<1><<<gg, 512, 0, stream>>>(comb, wob, out, 8192, 2048, 2048, 1.0f);  // O proj
}

// Round 19
// 549.133 us; speedup vs baseline: 1.0599x; 1.0300x over previous
//
#include <hip/hip_runtime.h>
#include <hip/hip_bf16.h>
#include <stdint.h>

#define S_LEN 2048
#define D_MODEL 2048
#define NH 16
#define HD_DIM 128
#define BATCH 4

typedef unsigned short u16;
typedef unsigned int u32;
typedef short s16x8 __attribute__((ext_vector_type(8)));
typedef float f32x4 __attribute__((ext_vector_type(4)));

__device__ __forceinline__ u16 f2b(float f) {
    union { float f; u32 u; } v; v.f = f;
    u32 r = v.u + 0x7FFFu + ((v.u >> 16) & 1u);
    return (u16)(r >> 16);
}

__device__ __forceinline__ u32 cvtpk(float lo, float hi) {
    u32 r;
    asm("v_cvt_pk_bf16_f32 %0, %1, %2" : "=v"(r) : "v"(lo), "v"(hi));
    return r;
}

__device__ __forceinline__ float exp2a(float x) {
    float r;
    asm("v_exp_f32 %0, %1" : "=v"(r) : "v"(x));
    return r;
}
__device__ __forceinline__ float max3a(float a, float b, float c) {
    float r;
    asm("v_max3_f32 %0, %1, %2, %3" : "=v"(r) : "v"(a), "v"(b), "v"(c));
    return r;
}

#define L2E 1.4426950408889634f

#define BAR()   asm volatile("s_barrier" ::: "memory")
#define LGKM0() asm volatile("s_waitcnt lgkmcnt(0)" ::: "memory")
#define VMW(n)  asm volatile("s_waitcnt vmcnt(" #n ")" ::: "memory")

// ---------------- single fused fp32->bf16 conversion launch ----------------
// weights -> wdst (contiguous x4); activations q->comb, k->d_out[0], v->d_out[1]
// (d_out used as scratch: overwritten by the final O-projection GEMM).
__global__ __launch_bounds__(256) void cvt_all(
    const float* __restrict__ wq, const float* __restrict__ wk,
    const float* __restrict__ wv, const float* __restrict__ wo,
    const float* __restrict__ q,  const float* __restrict__ k,
    const float* __restrict__ v,
    u16* __restrict__ wdst, u16* __restrict__ qdst,
    u16* __restrict__ kdst, u16* __restrict__ vdst) {
    int i = blockIdx.x * 256 + threadIdx.x;          // [0, 8388608)
    const float* src;
    u16* dst;
    if (i < 2097152) {                                // weights: 4 x 524288 n8-units
        const int seg = i >> 19, li = i & 524287;
        src = ((seg == 0) ? wq : (seg == 1) ? wk : (seg == 2) ? wv : wo) + (size_t)li * 8;
        dst = wdst + (size_t)i * 8;
    } else {                                          // activations: 3 x 2097152
        const int j = i - 2097152;
        const int seg = j >> 21, li = j & 2097151;
        src = ((seg == 0) ? q : (seg == 1) ? k : v) + (size_t)li * 8;
        dst = ((seg == 0) ? qdst : (seg == 1) ? kdst : vdst) + (size_t)li * 8;
    }
    const float4* p = reinterpret_cast<const float4*>(src);
    float4 a = p[0], b = p[1];
    s16x8 o;
    o[0] = (short)f2b(a.x); o[1] = (short)f2b(a.y);
    o[2] = (short)f2b(a.z); o[3] = (short)f2b(a.w);
    o[4] = (short)f2b(b.x); o[5] = (short)f2b(b.y);
    o[6] = (short)f2b(b.z); o[7] = (short)f2b(b.w);
    *reinterpret_cast<s16x8*>(dst) = o;
}

// ---------------- GEMM core (round-13/14 proven 8-phase 256x256 NT) ----------------
// Shared device body: C[M,N] = alpha * A[M,K] @ B[N,K]^T, M=8192 N=2048 K=2048.
template<int OUT_MODE>
__device__ __forceinline__ void gemm_body(const u16* __restrict__ Ab,
                                          const u16* __restrict__ Bw,
                                          void* __restrict__ Cv,
                                          int m0, int n0, float alpha,
                                          u16 (*lds)[2][256 * 64]) {
    const int M = 8192, N = 2048, K = 2048;
    const int t = threadIdx.x, lane = t & 63, w = t >> 6;
    const int wm = w >> 2, wn = w & 3;
    const int lr = lane & 15, lk = lane >> 4;
    const int NT = K >> 6;

    const int srow = t >> 3;
    const int spos = t & 7;
    const int scon = spos ^ (srow & 7);

    auto stage = [&](const u16* gbase, int grow0, int ldsT, int buf, int q, int kt) {
        const u16* src = gbase + (size_t)(grow0 + q * 64 + srow) * K + kt * 64 + scon * 8;
        u16* dst = &lds[buf][ldsT][(q * 64 + srow) * 64 + spos * 8];
        __builtin_amdgcn_global_load_lds(
            (const __attribute__((address_space(1))) void*)src,
            (__attribute__((address_space(3))) void*)dst, 16, 0, 0);
    };

    f32x4 acc[8][4];
#pragma unroll
    for (int i = 0; i < 8; ++i)
#pragma unroll
        for (int j = 0; j < 4; ++j) acc[i][j] = {0.f, 0.f, 0.f, 0.f};

    s16x8 a[4][2], b[4][2];

    stage(Bw, n0, 1, 0, 0, 0);
    stage(Bw, n0, 1, 0, 1, 0);
    stage(Bw, n0, 1, 0, 2, 0);
    stage(Bw, n0, 1, 0, 3, 0);
    stage(Ab, m0, 0, 0, 0, 0);
    stage(Ab, m0, 0, 0, 2, 0);
    stage(Ab, m0, 0, 0, 1, 0);
    stage(Ab, m0, 0, 0, 3, 0);
    VMW(2);
    BAR();

#define LDFRAG(base, row, kk) \
    (*(const s16x8*)((base) + (row) * 64 + ((((kk) * 4 + lk) ^ (lr & 7)) << 3)))

#define QUAD(mh, nh)                                                                   \
    __builtin_amdgcn_s_setprio(1);                                                     \
    _Pragma("unroll")                                                                  \
    for (int mf = 0; mf < 4; ++mf)                                                     \
        _Pragma("unroll")                                                              \
        for (int nf = 0; nf < 2; ++nf)                                                 \
            _Pragma("unroll")                                                          \
            for (int kk = 0; kk < 2; ++kk)                                             \
                acc[(mh) * 4 + mf][(nh) * 2 + nf] = __builtin_amdgcn_mfma_f32_16x16x32_bf16( \
                    a[mf][kk], b[(nh) * 2 + nf][kk], acc[(mh) * 4 + mf][(nh) * 2 + nf], 0, 0, 0); \
    __builtin_amdgcn_s_setprio(0);

    for (int kt = 0; kt < NT; ++kt) {
        const int buf = kt & 1;
        const u16* la = &lds[buf][0][0];
        const u16* lb = &lds[buf][1][0];
        const int nx = kt + 1;
        const bool st = nx < NT;

#pragma unroll
        for (int mf = 0; mf < 4; ++mf)
#pragma unroll
            for (int kk = 0; kk < 2; ++kk)
                a[mf][kk] = LDFRAG(la, wm * 128 + mf * 16 + lr, kk);
#pragma unroll
        for (int nf = 0; nf < 2; ++nf)
#pragma unroll
            for (int kk = 0; kk < 2; ++kk)
                b[nf][kk] = LDFRAG(lb, wn * 64 + nf * 16 + lr, kk);
        if (st) { stage(Bw, n0, 1, buf ^ 1, 0, nx); stage(Bw, n0, 1, buf ^ 1, 1, nx); }
        BAR();
        LGKM0();
        QUAD(0, 0);
        BAR();

#pragma unroll
        for (int nf = 2; nf < 4; ++nf)
#pragma unroll
            for (int kk = 0; kk < 2; ++kk)
                b[nf][kk] = LDFRAG(lb, wn * 64 + nf * 16 + lr, kk);
        if (st) { stage(Bw, n0, 1, buf ^ 1, 2, nx); stage(Bw, n0, 1, buf ^ 1, 3, nx); }
        BAR();
        LGKM0();
        QUAD(0, 1);
        if (kt == NT - 1) { VMW(0); } else { VMW(4); }
        BAR();

#pragma unroll
        for (int mf = 0; mf < 4; ++mf)
#pragma unroll
            for (int kk = 0; kk < 2; ++kk)
                a[mf][kk] = LDFRAG(la, wm * 128 + 64 + mf * 16 + lr, kk);
        if (st) { stage(Ab, m0, 0, buf ^ 1, 0, nx); stage(Ab, m0, 0, buf ^ 1, 2, nx); }
        BAR();
        LGKM0();
        QUAD(1, 0);
        BAR();

        if (st) { stage(Ab, m0, 0, buf ^ 1, 1, nx); stage(Ab, m0, 0, buf ^ 1, 3, nx); }
        BAR();
        QUAD(1, 1);
        VMW(2);
        BAR();
    }

#pragma unroll
    for (int i = 0; i < 8; ++i)
#pragma unroll
        for (int j = 0; j < 4; ++j) {
            int r0 = m0 + wm * 128 + (i >> 2) * 64 + (i & 3) * 16 + lk * 4;
            int c0 = n0 + wn * 64 + j * 16 + lr;
            if constexpr (OUT_MODE == 1) {
                float* C = (float*)Cv;
#pragma unroll
                for (int r = 0; r < 4; ++r) C[(size_t)(r0 + r) * N + c0] = acc[i][j][r] * alpha;
            } else {
                u16* C = (u16*)Cv;
#pragma unroll
                for (int r = 0; r < 4; ++r) C[(size_t)(r0 + r) * N + c0] = f2b(acc[i][j][r] * alpha);
            }
        }
}

// Q/K/V projections merged: 768 blocks (3 segments x 256); independent buffers
// (A: comb/dout0/dout1, C: qh/kh/vh) so concurrent segments cannot race.
// Drain of segment i overlaps fill of segment i+1 on each CU.
__global__ __launch_bounds__(512, 1) void gemm_qkv(
    const u16* __restrict__ A0, const u16* __restrict__ A1, const u16* __restrict__ A2,
    const u16* __restrict__ B0, const u16* __restrict__ B1, const u16* __restrict__ B2,
    u16* __restrict__ C0, u16* __restrict__ C1, u16* __restrict__ C2, float alpha0) {
    __shared__ u16 lds[2][2][256 * 64];
    const int flat = blockIdx.x;
    const int seg = flat >> 8, local = flat & 255;
    const u16* Ab = (seg == 0) ? A0 : (seg == 1) ? A1 : A2;
    const u16* Bw = (seg == 0) ? B0 : (seg == 1) ? B1 : B2;
    u16* Cv = (seg == 0) ? C0 : (seg == 1) ? C1 : C2;
    const float alpha = (seg == 0) ? alpha0 : 1.0f;
    // bijective XCD swizzle within the 256-block segment
    const int rmap = (local & 7) * 32 + (local >> 3);
    const int m0 = (rmap >> 3) * 256, n0 = (rmap & 7) * 256;
    gemm_body<0>(Ab, Bw, Cv, m0, n0, alpha, lds);
}

// final O projection (f32 out), standalone
__global__ __launch_bounds__(512, 1) void gemm_out(const u16* __restrict__ Ab,
                                                   const u16* __restrict__ Bw,
                                                   float* __restrict__ Cv) {
    __shared__ u16 lds[2][2][256 * 64];
    const int flat = blockIdx.x;
    const int rmap = (flat & 7) * 32 + (flat >> 3);
    const int m0 = (rmap >> 3) * 256, n0 = (rmap & 7) * 256;
    gemm_body<1>(Ab, Bw, Cv, m0, n0, 1.0f, lds);
}

// ---------------- flash attention (round-18 best, unchanged) ----------------
__global__ __launch_bounds__(512, 2) void attn_kernel(
    const u16* __restrict__ Qh, const u16* __restrict__ Kh, const u16* __restrict__ Vh,
    const float* __restrict__ mask, const float* __restrict__ kpad,
    u16* __restrict__ Comb) {
    __shared__ u16 Ks[2][64 * 128];
    __shared__ u16 Vt[2][128 * 64];

    const int t = threadIdx.x, lane = t & 63, w = t >> 6;   // w: 0..7
    const int lr = lane & 15, lk = lane >> 4;

    const int g = blockIdx.x;
    const int rm = (g & 7) * 64 + (g >> 3);      // 512 % 8 == 0: bijective
    const int qb = rm & 7, h = (rm >> 3) & 15, b = rm >> 7;  // qb fast (L3-friendly)
    const int q0w = qb * 256 + w * 32;
    const size_t rowBase = (size_t)b * S_LEN;
    const u16* Kb = Kh + rowBase * D_MODEL + h * HD_DIM;
    const u16* Vb = Vh + rowBase * D_MODEL + h * HD_DIM;

    s16x8 qf[2][4];
#pragma unroll
    for (int qi = 0; qi < 2; ++qi)
#pragma unroll
        for (int dc = 0; dc < 4; ++dc)
            qf[qi][dc] = *(const s16x8*)(Qh + (rowBase + q0w + qi * 16 + lr) * D_MODEL +
                                         h * HD_DIM + dc * 32 + lk * 8);

    f32x4 o[2][8];
#pragma unroll
    for (int qi = 0; qi < 2; ++qi)
#pragma unroll
        for (int dt = 0; dt < 8; ++dt) o[qi][dt] = {0.f, 0.f, 0.f, 0.f};
    float m_[2] = {-3e38f, -3e38f}, l_[2] = {0.f, 0.f};

    const int ksub = t >> 4;                          // 0..31
    const int kchunk = (t & 15) ^ (ksub & 7);
    const int vrow = t >> 3;                          // 0..63
    const int vc0 = (t & 7) * 16;
    const int vodd = vrow & 1;
    const int vp = t >> 4;                            // kv-pair 0..31

    s16x8 va0, va1;

    auto stageK = [&](int kv0, int nb) {
#pragma unroll
        for (int p = 0; p < 2; ++p) {
            const u16* src = Kb + (size_t)(kv0 + p * 32 + ksub) * D_MODEL + kchunk * 8;
            __builtin_amdgcn_global_load_lds(
                (const __attribute__((address_space(1))) void*)src,
                (__attribute__((address_space(3))) void*)(&Ks[nb][p * 4096 + t * 8]), 16, 0, 0);
        }
    };
    auto loadV = [&](int kv0) {
        const u16* p0 = Vb + (size_t)(kv0 + vrow) * D_MODEL + vc0;
        va0 = *(const s16x8*)p0;
        va1 = *(const s16x8*)(p0 + 8);
    };
    auto writeV = [&](int nb) {
        union VU { s16x8 v[2]; u32 uw[8]; u16 us[16]; };
        VU A;
        A.v[0] = va0; A.v[1] = va1;
        u32 ra[4];
#pragma unroll
        for (int i = 0; i < 4; ++i)
            ra[i] = (u32)__shfl_xor((int)(vodd ? A.uw[i] : A.uw[i + 4]), 8, 64);
#pragma unroll
        for (int e = 0; e < 8; ++e) {
            int d = vc0 + vodd * 8 + e;
            int swz = ((d >> 4) ^ (d & 7)) & 7;
            u16 rau = (u16)((ra[e >> 1] >> ((e & 1) * 16)) & 0xffff);
            u16 lo1, hi1;
            if (vodd) { lo1 = rau; hi1 = A.us[8 + e]; }
            else      { lo1 = A.us[e]; hi1 = rau; }
            int c1 = (vp >> 2) ^ swz;
            *(u32*)(&Vt[nb][d * 64 + c1 * 8 + (vp & 3) * 2]) = (u32)lo1 | ((u32)hi1 << 16);
        }
    };

    f32x4 mreg[2][4], kreg[4];
    auto loadMask = [&](int kv0) {
#pragma unroll
        for (int qi = 0; qi < 2; ++qi) {
            const float* mrow = mask + (size_t)(q0w + qi * 16 + lr) * S_LEN + kv0;
#pragma unroll
            for (int kt = 0; kt < 4; ++kt)
                mreg[qi][kt] = *(const f32x4*)(mrow + kt * 16 + lk * 4);
        }
#pragma unroll
        for (int kt = 0; kt < 4; ++kt)
            kreg[kt] = *(const f32x4*)(kpad + b * S_LEN + kv0 + kt * 16 + lk * 4);
    };

    stageK(0, 0);
    loadV(0);
    writeV(0);
    loadMask(0);
    __syncthreads();

    const int srcA = ((lk & 1) * 32) + lr;
    const int srcB = srcA + 16;

    for (int i = 0; i < 32; ++i) {
        const int cur = i & 1;
        const u16* ks = &Ks[cur][0];
        const u16* vt = &Vt[cur][0];
        const int kv0 = i * 64;

        if (i < 31) { stageK(kv0 + 64, cur ^ 1); loadV(kv0 + 64); }

        f32x4 sc[2][4];
#pragma unroll
        for (int qi = 0; qi < 2; ++qi)
#pragma unroll
            for (int kt = 0; kt < 4; ++kt) sc[qi][kt] = {0.f, 0.f, 0.f, 0.f};
        __builtin_amdgcn_s_setprio(1);
#pragma unroll
        for (int kt = 0; kt < 4; ++kt) {
            s16x8 kf[4];
#pragma unroll
            for (int dc = 0; dc < 4; ++dc)
                kf[dc] = *(const s16x8*)(&ks[(kt * 16 + lr) * 128 +
                                             (((dc * 4 + lk) ^ (lr & 7)) << 3)]);
#pragma unroll
            for (int dc = 0; dc < 4; ++dc) {
                sc[0][kt] = __builtin_amdgcn_mfma_f32_16x16x32_bf16(kf[dc], qf[0][dc], sc[0][kt], 0, 0, 0);
                sc[1][kt] = __builtin_amdgcn_mfma_f32_16x16x32_bf16(kf[dc], qf[1][dc], sc[1][kt], 0, 0, 0);
            }
        }
        __builtin_amdgcn_s_setprio(0);

        u32 lo[2][4], hi[2][4];
#pragma unroll
        for (int qi = 0; qi < 2; ++qi) {
            float s[16];
#pragma unroll
            for (int kt = 0; kt < 4; ++kt)
#pragma unroll
                for (int r = 0; r < 4; ++r)
                    s[kt * 4 + r] = fmaf(mreg[qi][kt][r], L2E,
                                         fmaf(kreg[kt][r], L2E, sc[qi][kt][r]));
            float t0 = max3a(s[0], s[1], s[2]);
            float t1 = max3a(s[3], s[4], s[5]);
            float t2 = max3a(s[6], s[7], s[8]);
            float t3 = max3a(s[9], s[10], s[11]);
            float t4 = max3a(s[12], s[13], s[14]);
            float mx = fmaxf(max3a(t0, t1, t2), max3a(t3, t4, s[15]));
            mx = fmaxf(mx, __shfl_xor(mx, 16, 64));
            mx = fmaxf(mx, __shfl_xor(mx, 32, 64));
            if (__any(mx > m_[qi] + 11.5f)) {
                float mn = fmaxf(m_[qi], mx);
                float fs = exp2a(m_[qi] - mn);
                m_[qi] = mn;
                l_[qi] *= fs;
#pragma unroll
                for (int r = 0; r < 4; ++r) {
                    float fsb = __shfl(fs, (lane & 48) | (lk * 4 + r), 64);
#pragma unroll
                    for (int dt = 0; dt < 8; ++dt) o[qi][dt][r] *= fsb;
                }
            }
#pragma unroll
            for (int e = 0; e < 16; ++e) s[e] = exp2a(s[e] - m_[qi]);
            float p0 = (s[0] + s[1]) + (s[2] + s[3]);
            float p1 = (s[4] + s[5]) + (s[6] + s[7]);
            float p2 = (s[8] + s[9]) + (s[10] + s[11]);
            float p3 = (s[12] + s[13]) + (s[14] + s[15]);
            float ls = (p0 + p1) + (p2 + p3);
            ls += __shfl_xor(ls, 16, 64);
            ls += __shfl_xor(ls, 32, 64);
            l_[qi] += ls;
#pragma unroll
            for (int kt = 0; kt < 4; ++kt) {
                lo[qi][kt] = cvtpk(s[kt * 4 + 0], s[kt * 4 + 1]);
                hi[qi][kt] = cvtpk(s[kt * 4 + 2], s[kt * 4 + 3]);
            }
        }

        if (i < 31) loadMask(kv0 + 64);

        s16x8 pf[2][2];
        const bool sel = (lk >> 1) & 1;
#pragma unroll
        for (int qi = 0; qi < 2; ++qi)
#pragma unroll
            for (int hh = 0; hh < 2; ++hh) {
                u32 w0a = (u32)__shfl((int)lo[qi][2 * hh], srcA, 64);
                u32 w0b = (u32)__shfl((int)lo[qi][2 * hh + 1], srcA, 64);
                u32 w1a = (u32)__shfl((int)hi[qi][2 * hh], srcA, 64);
                u32 w1b = (u32)__shfl((int)hi[qi][2 * hh + 1], srcA, 64);
                u32 w2a = (u32)__shfl((int)lo[qi][2 * hh], srcB, 64);
                u32 w2b = (u32)__shfl((int)lo[qi][2 * hh + 1], srcB, 64);
                u32 w3a = (u32)__shfl((int)hi[qi][2 * hh], srcB, 64);
                u32 w3b = (u32)__shfl((int)hi[qi][2 * hh + 1], srcB, 64);
                union { s16x8 v; u32 u[4]; } P;
                P.u[0] = sel ? w0b : w0a;
                P.u[1] = sel ? w1b : w1a;
                P.u[2] = sel ? w2b : w2a;
                P.u[3] = sel ? w3b : w3a;
                pf[qi][hh] = P.v;
            }

        __builtin_amdgcn_s_setprio(1);
#pragma unroll
        for (int dt = 0; dt < 8; ++dt) {
            int swz = dt ^ (lr & 7);
            s16x8 vf0 = *(const s16x8*)(&vt[(dt * 16 + lr) * 64 + ((lk ^ swz) << 3)]);
            s16x8 vf1 = *(const s16x8*)(&vt[(dt * 16 + lr) * 64 + (((4 + lk) ^ swz) << 3)]);
            o[0][dt] = __builtin_amdgcn_mfma_f32_16x16x32_bf16(pf[0][0], vf0, o[0][dt], 0, 0, 0);
            o[1][dt] = __builtin_amdgcn_mfma_f32_16x16x32_bf16(pf[1][0], vf0, o[1][dt], 0, 0, 0);
            o[0][dt] = __builtin_amdgcn_mfma_f32_16x16x32_bf16(pf[0][1], vf1, o[0][dt], 0, 0, 0);
            o[1][dt] = __builtin_amdgcn_mfma_f32_16x16x32_bf16(pf[1][1], vf1, o[1][dt], 0, 0, 0);
        }
        __builtin_amdgcn_s_setprio(0);

        if (i < 31) writeV(cur ^ 1);
        LGKM0();
        BAR();
    }

#pragma unroll
    for (int qi = 0; qi < 2; ++qi)
#pragma unroll
        for (int r = 0; r < 4; ++r) {
            float lb = __shfl(l_[qi], (lane & 48) | (lk * 4 + r), 64);
            float inv = 1.0f / lb;
            size_t row = rowBase + q0w + qi * 16 + lk * 4 + r;
            u16* dst = Comb + row * D_MODEL + h * HD_DIM + lr;
#pragma unroll
            for (int dt = 0; dt < 8; ++dt) dst[dt * 16] = f2b(o[qi][dt][r] * inv);
        }
}

extern "C" void kernel_launch(void* const* d_in, const int* in_sizes, int n_in,
                              void* d_out, int out_size, void* d_ws, size_t ws_size,
                              hipStream_t stream) {
    const float* q    = (const float*)d_in[0];
    const float* k    = (const float*)d_in[1];
    const float* v    = (const float*)d_in[2];
    const float* mask = (const float*)d_in[3];
    const float* kpad = (const float*)d_in[4];
    const float* wq   = (const float*)d_in[5];
    const float* wk   = (const float*)d_in[6];
    const float* wv   = (const float*)d_in[7];
    const float* wo   = (const float*)d_in[8];
    float* out = (float*)d_out;

    u16* wqb  = (u16*)d_ws;                 // 2048*2048 bf16 each, contiguous x4
    u16* wkb  = wqb + 4194304;
    u16* wvb  = wkb + 4194304;
    u16* wob  = wvb + 4194304;
    u16* qh   = wob + 4194304;              // 8192*2048 bf16 each
    u16* kh   = qh + 16777216;
    u16* vh   = kh + 16777216;
    u16* comb = vh + 16777216;
    // d_out (64 MB f32) doubles as 2 bf16 activation scratch slots pre-final-GEMM
    u16* dout0 = (u16*)d_out;
    u16* dout1 = dout0 + 16777216;

    // 1/sqrt(128) * log2(e): Q-projection alpha puts QK^T scores in log2 domain
    const float scale = 0.08838834764831845f * 1.4426950408889634f;

    // ONE conversion launch: weights -> wqb..wob; q->comb, k->dout0, v->dout1
    {
        dim3 gc(8388608 / 256);
        cvt_all<<<gc, 256, 0, stream>>>(wq, wk, wv, wo, q, k, v, wqb, comb, dout0, dout1);
    }

    // merged Q/K/V projections: 768 blocks, disjoint buffers per segment
    gemm_qkv<<<dim3(768), 512, 0, stream>>>(comb, dout0, dout1,
                                            wqb, wkb, wvb,
                                            qh, kh, vh, scale);

    attn_kernel<<<dim3(512), 512, 0, stream>>>(qh, kh, vh, mask, kpad, comb);

    gemm_out<<<dim3(256), 512, 0, stream>>>(comb, wob, out);
}